// Round 9
// baseline (2443.118 us; speedup 1.0000x reference)
//
#include <hip/hip_runtime.h>
#include <hip/hip_bf16.h>

// Problem constants: B=8, T=512, V=32000, E=256, H=512
typedef __attribute__((ext_vector_type(8))) short short8;
typedef __attribute__((ext_vector_type(4))) float f32x4;
typedef __attribute__((ext_vector_type(4))) unsigned int u32x4;

__device__ __forceinline__ void glds16(const void* g, void* l) {
  __builtin_amdgcn_global_load_lds(
      (const __attribute__((address_space(1))) unsigned int*)g,
      (__attribute__((address_space(3))) unsigned int*)l, 16, 0, 0);
}

// Barrier that drains ONLY LDS ops (lgkmcnt) — global stores stay async.
__device__ __forceinline__ void bar_lds() {
  asm volatile("s_waitcnt lgkmcnt(0)\n\ts_barrier" ::: "memory");
}

__device__ __forceinline__ float fast_tanh(float x) {
  float e = __expf(2.0f * x);
  return (e - 1.0f) * __builtin_amdgcn_rcpf(e + 1.0f);
}

__device__ __forceinline__ unsigned short bfh(float f) {
  __hip_bfloat16 h = __float2bfloat16(f);
  return *reinterpret_cast<unsigned short*>(&h);
}
__device__ __forceinline__ float bf2f(unsigned short u) {
  unsigned v = ((unsigned)u) << 16;
  float f;
  __builtin_memcpy(&f, &v, 4);
  return f;
}
__device__ __forceinline__ short bf16r(float f) { return (short)bfh(f); }

union FragU {
  unsigned int u[4];
  short8 s;
};

// ---------------------------------------------------------------- K1: xin = emb(x) @ W_ih^T + b_ih
__global__ __launch_bounds__(256) void k_xin(const int* __restrict__ x, const float* __restrict__ embed,
                                             const float* __restrict__ W_ih, const float* __restrict__ b_ih,
                                             float* __restrict__ xin) {
  __shared__ float At[64][128];
  __shared__ float Bt[128][64];
  const int tid = threadIdx.x;
  const int bt0 = blockIdx.x * 64, j0 = blockIdx.y * 64;
  const int ty = tid >> 4, tx = tid & 15;
  const int lane = tid & 63, cgrp = tid >> 6;
  float acc[4][4] = {};
  for (int kc = 0; kc < 256; kc += 128) {
#pragma unroll
    for (int rr = 0; rr < 8; ++rr) {
      int row = rr * 8 + (tid >> 5);
      int col = (tid & 31) * 4;
      int tok = x[bt0 + row];
      float4 v = make_float4(0.f, 0.f, 0.f, 0.f);
      if (tok != 0) v = *(const float4*)&embed[(size_t)tok * 256 + kc + col];
      *(float4*)&At[row][col] = v;
    }
#pragma unroll
    for (int cc = 0; cc < 8; ++cc) {
      int col = cgrp * 32 + cc * 4;
      float4 v = *(const float4*)&W_ih[(size_t)(j0 + lane) * 256 + kc + col];
      Bt[col + 0][lane] = v.x; Bt[col + 1][lane] = v.y;
      Bt[col + 2][lane] = v.z; Bt[col + 3][lane] = v.w;
    }
    __syncthreads();
    for (int kk = 0; kk < 128; ++kk) {
      float bv[4];
#pragma unroll
      for (int c = 0; c < 4; ++c) bv[c] = Bt[kk][tx * 4 + c];
#pragma unroll
      for (int a = 0; a < 4; ++a) {
        float av = At[ty * 4 + a][kk];
#pragma unroll
        for (int c = 0; c < 4; ++c) acc[a][c] = fmaf(av, bv[c], acc[a][c]);
      }
    }
    __syncthreads();
  }
#pragma unroll
  for (int a = 0; a < 4; ++a) {
    int m = bt0 + ty * 4 + a;
#pragma unroll
    for (int c = 0; c < 4; ++c) {
      int j = j0 + tx * 4 + c;
      xin[(size_t)m * 512 + j] = acc[a][c] + b_ih[j];
    }
  }
}

// ---------------------------------------------------------------- K2: persistent RNN scan — R4 structure, 16B-wide mailbox ops
// Blocks 0..7: workers. Block owns j-window [64*blk, 64*blk+64).
// mbox[dst 0..7][slot 0..15][2048 u64]: PROVEN R4 private-mailbox transport.
// ALL mailbox traffic (poll loads, publish stores, re-sentinel stores) uses
// 16B global_*_dwordx4 with sc0 sc1 (system-scope relaxed) inline asm:
// half the memory-side transactions of 8B atomics (the R4 bottleneck:
// WRITE_SIZE 344 MB from ~25 MB of data). Sentinel validation checks ALL
// dwords (tearing-safe: torn visibility shows a 0xFFFFFFFF dword -> retry).
// Blocks 8..135: side-work — convert fc_W to bf16 while the RNN runs.
__global__ __launch_bounds__(512) void k_rnn(const float* __restrict__ xin, const float* __restrict__ W_hh,
                                             const float* __restrict__ b_hh, const int* __restrict__ lengths,
                                             unsigned long long* mbox, float* __restrict__ out,
                                             unsigned short* __restrict__ feats,
                                             const float* __restrict__ fcW, unsigned short* __restrict__ fcWb) {
  const int tid = threadIdx.x;
  if (blockIdx.x >= 8) {
    const size_t stride = (size_t)(gridDim.x - 8) * 512 * 8;
    for (size_t i = ((size_t)(blockIdx.x - 8) * 512 + tid) * 8; i < 32768000ull; i += stride) {
      float4 a = *(const float4*)(fcW + i);
      float4 b = *(const float4*)(fcW + i + 4);
      short8 v;
      v[0] = bf16r(a.x); v[1] = bf16r(a.y); v[2] = bf16r(a.z); v[3] = bf16r(a.w);
      v[4] = bf16r(b.x); v[5] = bf16r(b.y); v[6] = bf16r(b.z); v[7] = bf16r(b.w);
      *(short8*)(fcWb + i) = v;
    }
    return;
  }
  const int blk = blockIdx.x;
  const int w = tid >> 6, l = tid & 63;
  const int jt = w & 3, kh = w >> 2;
  const int j16 = blk * 64 + jt * 16;
  const int r = l & 15;   // A row (= batch b), valid r<8
  const int g = l >> 4;   // k-group
  const int n = l & 15;   // B col (= j within tile)

  __shared__ unsigned long long stg[2048];  // 16 KB staged h, granule-swizzled
  __shared__ f32x4 Cbuf[4][64];             // cross-K-half partial sums
  __shared__ float hLf[8][64];              // exact fp32 h slice (for out/feats)
  __shared__ unsigned int hL32[8][64];      // packed {hi,lo} bf16 (for publish)
  __shared__ int nflag[2];

  // ---- preload W fragments (bf16 hi/lo), 8 chunks per wave (proven layout)
  short8 bhi[8], blo[8];
  {
    const float* wrow = &W_hh[(size_t)(j16 + n) * 512];
#pragma unroll
    for (int c8 = 0; c8 < 8; ++c8) {
      int c = kh * 8 + c8;
      const float* wp = wrow + c * 32 + g * 8;
      float4 wa = *(const float4*)wp;
      float4 wb = *(const float4*)(wp + 4);
      float wv[8] = {wa.x, wa.y, wa.z, wa.w, wb.x, wb.y, wb.z, wb.w};
#pragma unroll
      for (int e = 0; e < 8; ++e) {
        unsigned short h = bfh(wv[e]);
        bhi[c8][e] = (short)h;
        blo[c8][e] = (short)bfh(wv[e] - bf2f(h));
      }
    }
  }

  // ---- per-lane epilogue constants (waves 0..3, lanes 0..31)
  float bj = 0.f, xv[4];
  if (w < 4 && l < 32) {
    bj = b_hh[j16 + n];
#pragma unroll
    for (int i = 0; i < 4; ++i)
      xv[i] = xin[((size_t)(g * 4 + i) * 512 + 0) * 512 + j16 + n];  // t=0
  }
  const int mylen = lengths[(tid >> 6) & 7];  // b = tid>>6 for out-store phase

  if (tid < 2) nflag[tid] = 0;
  __syncthreads();

  // granule swizzle: LDS granule = memGran ^ ((memGran>>6)&3). Preserves 32B
  // granules; read side memGran>>6 == r -> XOR key r&3. (R4-proven, 0 conflicts)
  const int sgran = tid ^ ((tid >> 6) & 3);

  for (int t = 0; t < 512; ++t) {
    // ================ poll own mailbox slot (t&15), stage into LDS ================
    {
      unsigned long long* src = mbox + ((size_t)blk * 16 + (t & 15)) * 2048 + tid * 4;
      bool mine = false;
      int round = 0;
      while (true) {
        if (!mine) {
          u32x4 A, B2;
          asm volatile(
              "global_load_dwordx4 %0, %2, off sc0 sc1\n\t"
              "global_load_dwordx4 %1, %2, off offset:16 sc0 sc1\n\t"
              "s_waitcnt vmcnt(0)"
              : "=&v"(A), "=&v"(B2)
              : "v"(src)
              : "memory");
          bool ok = true;
#pragma unroll
          for (int q = 0; q < 4; ++q) ok = ok && (A[q] != 0xFFFFFFFFu) && (B2[q] != 0xFFFFFFFFu);
          if (ok) {
            mine = true;
            stg[sgran * 4 + 0] = (unsigned long long)A[0] | ((unsigned long long)A[1] << 32);
            stg[sgran * 4 + 1] = (unsigned long long)A[2] | ((unsigned long long)A[3] << 32);
            stg[sgran * 4 + 2] = (unsigned long long)B2[0] | ((unsigned long long)B2[1] << 32);
            stg[sgran * 4 + 3] = (unsigned long long)B2[2] | ((unsigned long long)B2[3] << 32);
            u32x4 S;
            S[0] = S[1] = S[2] = S[3] = 0xFFFFFFFFu;
            asm volatile(
                "global_store_dwordx4 %0, %1, off sc0 sc1\n\t"
                "global_store_dwordx4 %0, %1, off offset:16 sc0 sc1"
                :: "v"(src), "v"(S)
                : "memory");
          }
        }
        int p = round & 1;
        if (!mine) nflag[p] = 1;
        bar_lds();
        int bad = nflag[p];
        if (tid == 0) nflag[p ^ 1] = 0;
        bar_lds();
        if (!bad) break;
        if (++round == (1 << 16)) break;  // bug guard -> visible absmax failure
      }
    }

    // ================ MFMA from LDS-staged fragments ================
    f32x4 acc0 = {}, acc1 = {};
#pragma unroll
    for (int c8 = 0; c8 < 8; ++c8) {
      FragU ah, al;
      if (r < 8) {
        int gran = r * 64 + kh * 32 + c8 * 4 + g;
        int gs = (gran ^ (r & 3)) * 4;
        unsigned long long u0 = stg[gs + 0], u1 = stg[gs + 1];
        unsigned long long u2 = stg[gs + 2], u3 = stg[gs + 3];
        ah.u[0] = (unsigned)u0; al.u[0] = (unsigned)(u0 >> 32);
        ah.u[1] = (unsigned)u1; al.u[1] = (unsigned)(u1 >> 32);
        ah.u[2] = (unsigned)u2; al.u[2] = (unsigned)(u2 >> 32);
        ah.u[3] = (unsigned)u3; al.u[3] = (unsigned)(u3 >> 32);
      } else {
        ah.u[0] = ah.u[1] = ah.u[2] = ah.u[3] = 0u;
        al.u[0] = al.u[1] = al.u[2] = al.u[3] = 0u;
      }
      if (c8 & 1) {
        acc1 = __builtin_amdgcn_mfma_f32_16x16x32_bf16(ah.s, bhi[c8], acc1, 0, 0, 0);
        acc1 = __builtin_amdgcn_mfma_f32_16x16x32_bf16(ah.s, blo[c8], acc1, 0, 0, 0);
        acc1 = __builtin_amdgcn_mfma_f32_16x16x32_bf16(al.s, bhi[c8], acc1, 0, 0, 0);
      } else {
        acc0 = __builtin_amdgcn_mfma_f32_16x16x32_bf16(ah.s, bhi[c8], acc0, 0, 0, 0);
        acc0 = __builtin_amdgcn_mfma_f32_16x16x32_bf16(ah.s, blo[c8], acc0, 0, 0, 0);
        acc0 = __builtin_amdgcn_mfma_f32_16x16x32_bf16(al.s, bhi[c8], acc0, 0, 0, 0);
      }
    }
    f32x4 tot = acc0 + acc1;

    // ================ cross-K-half reduce + tanh (R4 structure) ================
    if (w >= 4) Cbuf[w - 4][l] = tot;
    bar_lds();  // B1
    if (w < 4) {
      tot += Cbuf[w][l];
      if (l < 32) {
#pragma unroll
        for (int i = 0; i < 4; ++i) {
          int b = g * 4 + i;
          float hn = fast_tanh(xv[i] + tot[i] + bj);
          hLf[b][jt * 16 + n] = hn;
          unsigned hi = bfh(hn);
          unsigned lo = bfh(hn - bf2f((unsigned short)hi));
          hL32[b][jt * 16 + n] = hi | (lo << 16);
        }
        int tt = (t < 511) ? t + 1 : 511;
#pragma unroll
        for (int i = 0; i < 4; ++i)
          xv[i] = xin[((size_t)(g * 4 + i) * 512 + tt) * 512 + j16 + n];
      }
    }
    bar_lds();  // B2: hLf / hL32 ready

    // ================ out (fp32) + feats (bf16) store, all 512 threads ==========
    {
      int b = tid >> 6, jl = tid & 63;
      float hv = hLf[b][jl];
      hv = (t < mylen) ? hv : 0.f;
      out[((size_t)b * 512 + t) * 512 + blk * 64 + jl] = hv;
      feats[((size_t)b * 512 + t) * 1024 + blk * 64 + jl] = bfh(hv);
    }

    // ================ publish h_{t+1}: wave w -> mailbox w, 2x dwordx4/lane =====
    if (t < 511) {
      unsigned long long* dst = mbox + ((size_t)w * 16 + ((t + 1) & 15)) * 2048 + blk * 32;
      const int e0 = (l & 15) * 4;
#pragma unroll
      for (int k2 = 0; k2 < 2; ++k2) {
        int b = (l >> 4) + k2 * 4;
        unsigned a0 = hL32[b][e0 + 0], a1 = hL32[b][e0 + 1];
        unsigned a2 = hL32[b][e0 + 2], a3 = hL32[b][e0 + 3];
        u32x4 val;
        val[0] = (a0 & 0xffffu) | (a1 << 16);          // hi-pair of word 2(l&15)
        val[1] = (a0 >> 16) | (a1 & 0xffff0000u);      // lo-pair
        val[2] = (a2 & 0xffffu) | (a3 << 16);          // hi-pair of word 2(l&15)+1
        val[3] = (a2 >> 16) | (a3 & 0xffff0000u);      // lo-pair
        unsigned long long* p = dst + (size_t)b * 256 + (l & 15) * 2;
        asm volatile("global_store_dwordx4 %0, %1, off sc0 sc1" :: "v"(p), "v"(val) : "memory");
      }
    }
    // no trailing barrier: next step's poll barrier pair paces LDS reuse.
  }
}

// ---------------------------------------------------------------- K3: q = out@W1^T ; kT = out@W2^T + b
template <int MODE>
__global__ __launch_bounds__(256) void k_qk(const float* __restrict__ out, const float* __restrict__ attn_W,
                                            const float* __restrict__ attn_b, float* __restrict__ dst) {
  __shared__ float At[64][128];
  __shared__ float Bt[128][64];
  const int tid = threadIdx.x;
  const int bt0 = blockIdx.x * 64, j0 = blockIdx.y * 64;
  const int ty = tid >> 4, tx = tid & 15;
  const int lane = tid & 63, cgrp = tid >> 6;
  float acc[4][4] = {};
  for (int kc = 0; kc < 512; kc += 128) {
#pragma unroll
    for (int rr = 0; rr < 8; ++rr) {
      int row = rr * 8 + (tid >> 5);
      int col = (tid & 31) * 4;
      *(float4*)&At[row][col] = *(const float4*)&out[((size_t)bt0 + row) * 512 + kc + col];
    }
#pragma unroll
    for (int cc = 0; cc < 8; ++cc) {
      int col = cgrp * 32 + cc * 4;
      float4 v = *(const float4*)&attn_W[(size_t)(j0 + lane) * 1024 + (MODE ? 512 : 0) + kc + col];
      Bt[col + 0][lane] = v.x; Bt[col + 1][lane] = v.y;
      Bt[col + 2][lane] = v.z; Bt[col + 3][lane] = v.w;
    }
    __syncthreads();
    for (int kk = 0; kk < 128; ++kk) {
      float bv[4];
#pragma unroll
      for (int c = 0; c < 4; ++c) bv[c] = Bt[kk][tx * 4 + c];
#pragma unroll
      for (int a = 0; a < 4; ++a) {
        float av = At[ty * 4 + a][kk];
#pragma unroll
        for (int c = 0; c < 4; ++c) acc[a][c] = fmaf(av, bv[c], acc[a][c]);
      }
    }
    __syncthreads();
  }
#pragma unroll
  for (int a = 0; a < 4; ++a) {
    int bt = bt0 + ty * 4 + a;
#pragma unroll
    for (int c = 0; c < 4; ++c) {
      int j = j0 + tx * 4 + c;
      if (MODE == 0) {
        dst[(size_t)bt * 512 + j] = acc[a][c];
      } else {
        int bb = bt >> 9, tt = bt & 511;
        dst[((size_t)bb * 512 + j) * 512 + tt] = acc[a][c] + attn_b[j];
      }
    }
  }
}

// ---------------------------------------------------------------- K4: p[b][t][s] = exp(score-20) masked  (+ fused rowsum -> invl)
__global__ __launch_bounds__(256) void k_scores(const float* __restrict__ q, const float* __restrict__ kT,
                                                const float* __restrict__ attn_v, const float* __restrict__ attn_v_b,
                                                const int* __restrict__ lengths, float* __restrict__ pbuf,
                                                float* __restrict__ invl) {
  const int b = blockIdx.x, t0 = blockIdx.y * 4;
  const int tid = threadIdx.x;
  __shared__ float qL[4][512];
  __shared__ float vL[512];
  __shared__ float red[4][4];
  for (int i = tid; i < 4 * 512; i += 256) {
    int rr = i >> 9, h = i & 511;
    qL[rr][h] = q[((size_t)b * 512 + t0 + rr) * 512 + h];
  }
  for (int i = tid; i < 512; i += 256) vL[i] = attn_v[i];
  const float vb = attn_v_b[0];
  const int len = lengths[b];
  __syncthreads();
  const int s_hi = min(t0 + 3, len - 1);
  const float* kTb = kT + (size_t)b * 512 * 512;
  float psum[4] = {0.f, 0.f, 0.f, 0.f};
#pragma unroll
  for (int si = 0; si < 2; ++si) {
    int s = tid + si * 256;
    float acc[4] = {0.f, 0.f, 0.f, 0.f};
    if (s <= s_hi) {
      for (int h = 0; h < 512; ++h) {
        float kv = kTb[(size_t)h * 512 + s];
        float vh = vL[h];
#pragma unroll
        for (int rr = 0; rr < 4; ++rr) acc[rr] = fmaf(vh, fast_tanh(qL[rr][h] + kv), acc[rr]);
      }
    }
#pragma unroll
    for (int rr = 0; rr < 4; ++rr) {
      int t = t0 + rr;
      bool valid = (s <= t) && (s < len);
      float p = valid ? __expf(acc[rr] + vb - 20.f) : 0.f;
      pbuf[((size_t)b * 512 + t) * 512 + s] = p;
      psum[rr] += p;
    }
  }
  const int wv = tid >> 6, ln = tid & 63;
#pragma unroll
  for (int rr = 0; rr < 4; ++rr) {
    float v = psum[rr];
#pragma unroll
    for (int m = 1; m < 64; m <<= 1) v += __shfl_xor(v, m);
    if (ln == 0) red[wv][rr] = v;
  }
  __syncthreads();
  if (tid < 4) {
    float s = red[0][tid] + red[1][tid] + red[2][tid] + red[3][tid];
    invl[(size_t)b * 512 + t0 + tid] = 1.0f / s;
  }
}

// ---------------------------------------------------------------- K6: feats[:, 512:1024] = bf16((p @ out) * invl)
__global__ __launch_bounds__(256) void k_context(const float* __restrict__ pbuf, const float* __restrict__ out,
                                                 const float* __restrict__ invl, unsigned short* __restrict__ feats) {
  __shared__ float Pt[64][128];
  __shared__ float Ot[128][64];
  const int b = blockIdx.z, t0 = blockIdx.y * 64, h0 = blockIdx.x * 64;
  const int tid = threadIdx.x, ty = tid >> 4, tx = tid & 15;
  float acc[4][4] = {};
  for (int sc = 0; sc < 512; sc += 128) {
#pragma unroll
    for (int rr = 0; rr < 8; ++rr) {
      int row = rr * 8 + (tid >> 5);
      int col = (tid & 31) * 4;
      *(float4*)&Pt[row][col] = *(const float4*)&pbuf[((size_t)b * 512 + t0 + row) * 512 + sc + col];
    }
#pragma unroll
    for (int rr = 0; rr < 8; ++rr) {
      int srow = rr * 16 + (tid >> 4);
      int col = (tid & 15) * 4;
      *(float4*)&Ot[srow][col] = *(const float4*)&out[((size_t)b * 512 + sc + srow) * 512 + h0 + col];
    }
    __syncthreads();
    for (int kk = 0; kk < 128; ++kk) {
      float ov[4];
#pragma unroll
      for (int c = 0; c < 4; ++c) ov[c] = Ot[kk][tx * 4 + c];
#pragma unroll
      for (int a = 0; a < 4; ++a) {
        float pv = Pt[ty * 4 + a][kk];
#pragma unroll
        for (int c = 0; c < 4; ++c) acc[a][c] = fmaf(pv, ov[c], acc[a][c]);
      }
    }
    __syncthreads();
  }
#pragma unroll
  for (int a = 0; a < 4; ++a) {
    int t = t0 + ty * 4 + a;
    float il = invl[b * 512 + t];
#pragma unroll
    for (int c = 0; c < 4; ++c) {
      int h = h0 + tx * 4 + c;
      feats[((size_t)b * 512 + t) * 1024 + 512 + h] = (unsigned short)bf16r(acc[a][c] * il);
    }
  }
}

// ---------------------------------------------------------------- K7: logits = feats @ fc_W^T + fc_b (bf16 MFMA, XCD-swizzled)
__global__ __launch_bounds__(256) void k_logits(const unsigned short* __restrict__ A,
                                                const unsigned short* __restrict__ Bw,
                                                const float* __restrict__ bias, float* __restrict__ C) {
  const int linb = blockIdx.x;
  const int xcd = linb & 7, pos = linb >> 3;
  const int m0 = (xcd * 4 + (pos & 3)) * 128;
  const int n0 = (pos >> 2) * 128;
  __shared__ unsigned short As[128 * 64];
  __shared__ unsigned short Bs[128 * 64];
  const int tid = threadIdx.x;
  const int wave = tid >> 6, lane = tid & 63;
  const int wm = (wave >> 1) * 64, wn = (wave & 1) * 64;
  const int lo16 = lane & 15, oct = lane >> 4;
  f32x4 acc[4][4] = {};
  for (int kt = 0; kt < 1024; kt += 64) {
#pragma unroll
    for (int i = 0; i < 4; ++i) {
      int ci = wave * 4 + i;
      int mrow = ci * 8 + (lane >> 3);
      int k8 = (lane & 7) * 8;
      glds16(&A[(size_t)(m0 + mrow) * 1024 + kt + k8], &As[ci * 512]);
      glds16(&Bw[(size_t)(n0 + mrow) * 1024 + kt + k8], &Bs[ci * 512]);
    }
    __syncthreads();
#pragma unroll
    for (int kk = 0; kk < 2; ++kk) {
      short8 af[4], bf[4];
#pragma unroll
      for (int i = 0; i < 4; ++i)
        af[i] = *(const short8*)&As[(wm + i * 16 + lo16) * 64 + kk * 32 + oct * 8];
#pragma unroll
      for (int jn = 0; jn < 4; ++jn)
        bf[jn] = *(const short8*)&Bs[(wn + jn * 16 + lo16) * 64 + kk * 32 + oct * 8];
#pragma unroll
      for (int i = 0; i < 4; ++i)
#pragma unroll
        for (int jn = 0; jn < 4; ++jn)
          acc[i][jn] = __builtin_amdgcn_mfma_f32_16x16x32_bf16(af[i], bf[jn], acc[i][jn], 0, 0, 0);
    }
    __syncthreads();
  }
#pragma unroll
  for (int jn = 0; jn < 4; ++jn) {
    int nn = n0 + wn + jn * 16 + lo16;
    float bv = bias[nn];
#pragma unroll
    for (int i = 0; i < 4; ++i) {
      int mbase = m0 + wm + i * 16 + oct * 4;
#pragma unroll
      for (int rr = 0; rr < 4; ++rr)
        C[(size_t)(mbase + rr) * 32000 + nn] = acc[i][jn][rr] + bv;
    }
  }
}

// ---------------------------------------------------------------- launch
extern "C" void kernel_launch(void* const* d_in, const int* in_sizes, int n_in,
                              void* d_out, int out_size, void* d_ws, size_t ws_size,
                              hipStream_t stream) {
  const int* x = (const int*)d_in[0];
  const int* lengths = (const int*)d_in[1];
  const float* embed = (const float*)d_in[2];
  const float* W_ih = (const float*)d_in[3];
  const float* W_hh = (const float*)d_in[4];
  const float* b_ih = (const float*)d_in[5];
  const float* b_hh = (const float*)d_in[6];
  const float* attn_W = (const float*)d_in[7];
  const float* attn_b = (const float*)d_in[8];
  const float* attn_v = (const float*)d_in[9];
  const float* attn_v_b = (const float*)d_in[10];
  const float* fc_W = (const float*)d_in[11];
  const float* fc_b = (const float*)d_in[12];
  float* logits = (float*)d_out;

  char* ws = (char*)d_ws;
  const size_t MB8 = 8388608;
  float* xin  = (float*)(ws);
  float* outp = (float*)(ws + 1 * MB8);
  float* q    = (float*)(ws + 2 * MB8);
  float* kT   = (float*)(ws + 3 * MB8);
  float* pbuf = (float*)(ws + 4 * MB8);
  float* invl = (float*)(ws + 5 * MB8);
  unsigned short* feats = (unsigned short*)(ws + 5 * MB8 + 16384);
  unsigned short* fcWb  = (unsigned short*)(ws + 6 * MB8 + 16384);
  // mbox aliases pbuf: [8 dst][16 slots][16 KB] = 2 MB. Dead once k_rnn
  // completes; k_scores then fully overwrites pbuf.
  unsigned long long* mbox = (unsigned long long*)pbuf;

  hipMemsetAsync(mbox, 0xFF, 8 * 16 * 16384, stream);  // sentinel all ring slots
  for (int d = 0; d < 8; ++d)                          // slot 0 of each mailbox = h_0 = 0
    hipMemsetAsync((char*)mbox + (size_t)d * 16 * 16384, 0x00, 16384, stream);
  k_xin<<<dim3(64, 8), 256, 0, stream>>>(x, embed, W_ih, b_ih, xin);
  k_rnn<<<136, 512, 0, stream>>>(xin, W_hh, b_hh, lengths, mbox, outp, feats, fc_W, fcWb);
  k_qk<0><<<dim3(64, 8), 256, 0, stream>>>(outp, attn_W, attn_b, q);
  k_qk<1><<<dim3(64, 8), 256, 0, stream>>>(outp, attn_W, attn_b, kT);
  k_scores<<<dim3(8, 128), 256, 0, stream>>>(q, kT, attn_v, attn_v_b, lengths, pbuf, invl);
  k_context<<<dim3(8, 8, 8), 256, 0, stream>>>(pbuf, outp, invl, feats);
  k_logits<<<8000, 256, 0, stream>>>(feats, fcWb, fc_b, logits);
}

// Round 10
// 2249.596 us; speedup vs baseline: 1.0860x; 1.0860x over previous
//
#include <hip/hip_runtime.h>
#include <hip/hip_bf16.h>

// Problem constants: B=8, T=512, V=32000, E=256, H=512
typedef __attribute__((ext_vector_type(8))) short short8;
typedef __attribute__((ext_vector_type(4))) float f32x4;
typedef __attribute__((ext_vector_type(4))) unsigned int u32x4;

__device__ __forceinline__ void glds16(const void* g, void* l) {
  __builtin_amdgcn_global_load_lds(
      (const __attribute__((address_space(1))) unsigned int*)g,
      (__attribute__((address_space(3))) unsigned int*)l, 16, 0, 0);
}

// Barrier that drains ONLY LDS ops (lgkmcnt) — global stores stay async.
__device__ __forceinline__ void bar_lds() {
  asm volatile("s_waitcnt lgkmcnt(0)\n\ts_barrier" ::: "memory");
}

__device__ __forceinline__ float fast_tanh(float x) {
  float e = __expf(2.0f * x);
  return (e - 1.0f) * __builtin_amdgcn_rcpf(e + 1.0f);
}

__device__ __forceinline__ unsigned short bfh(float f) {
  __hip_bfloat16 h = __float2bfloat16(f);
  return *reinterpret_cast<unsigned short*>(&h);
}
__device__ __forceinline__ float bf2f(unsigned short u) {
  unsigned v = ((unsigned)u) << 16;
  float f;
  __builtin_memcpy(&f, &v, 4);
  return f;
}
__device__ __forceinline__ short bf16r(float f) { return (short)bfh(f); }

union FragU {
  unsigned int u[4];
  short8 s;
};

// ---------------------------------------------------------------- K1: xin = emb(x) @ W_ih^T + b_ih
__global__ __launch_bounds__(256) void k_xin(const int* __restrict__ x, const float* __restrict__ embed,
                                             const float* __restrict__ W_ih, const float* __restrict__ b_ih,
                                             float* __restrict__ xin) {
  __shared__ float At[64][128];
  __shared__ float Bt[128][64];
  const int tid = threadIdx.x;
  const int bt0 = blockIdx.x * 64, j0 = blockIdx.y * 64;
  const int ty = tid >> 4, tx = tid & 15;
  const int lane = tid & 63, cgrp = tid >> 6;
  float acc[4][4] = {};
  for (int kc = 0; kc < 256; kc += 128) {
#pragma unroll
    for (int rr = 0; rr < 8; ++rr) {
      int row = rr * 8 + (tid >> 5);
      int col = (tid & 31) * 4;
      int tok = x[bt0 + row];
      float4 v = make_float4(0.f, 0.f, 0.f, 0.f);
      if (tok != 0) v = *(const float4*)&embed[(size_t)tok * 256 + kc + col];
      *(float4*)&At[row][col] = v;
    }
#pragma unroll
    for (int cc = 0; cc < 8; ++cc) {
      int col = cgrp * 32 + cc * 4;
      float4 v = *(const float4*)&W_ih[(size_t)(j0 + lane) * 256 + kc + col];
      Bt[col + 0][lane] = v.x; Bt[col + 1][lane] = v.y;
      Bt[col + 2][lane] = v.z; Bt[col + 3][lane] = v.w;
    }
    __syncthreads();
    for (int kk = 0; kk < 128; ++kk) {
      float bv[4];
#pragma unroll
      for (int c = 0; c < 4; ++c) bv[c] = Bt[kk][tx * 4 + c];
#pragma unroll
      for (int a = 0; a < 4; ++a) {
        float av = At[ty * 4 + a][kk];
#pragma unroll
        for (int c = 0; c < 4; ++c) acc[a][c] = fmaf(av, bv[c], acc[a][c]);
      }
    }
    __syncthreads();
  }
#pragma unroll
  for (int a = 0; a < 4; ++a) {
    int m = bt0 + ty * 4 + a;
#pragma unroll
    for (int c = 0; c < 4; ++c) {
      int j = j0 + tx * 4 + c;
      xin[(size_t)m * 512 + j] = acc[a][c] + b_ih[j];
    }
  }
}

// ---------------------------------------------------------------- K2: persistent RNN scan — R9 + per-lane sentinel spin
// Blocks 0..7: workers. Block owns j-window [64*blk, 64*blk+64).
// mbox[dst 0..7][slot 0..15][2048 u64]: private-mailbox transport, 16B
// dwordx4 sc0 sc1 ops (R9-proven). POLL: each lane spins independently on its
// own 32B (all-8-dword sentinel validation, tearing-safe), stages its granule
// to LDS the moment data lands, then ONE bar_lds — removes the flag-protocol's
// round quantization (block advances with the slowest lane, not the slowest
// round). LDS cross-step ordering is preserved by B0/B1/B2:
//   reads(stg)@t < B1(t) < B2(t) < poll(t+1) < writes(stg)@t+1.
// Blocks 8..135: side-work — convert fc_W to bf16 while the RNN runs.
__global__ __launch_bounds__(512) void k_rnn(const float* __restrict__ xin, const float* __restrict__ W_hh,
                                             const float* __restrict__ b_hh, const int* __restrict__ lengths,
                                             unsigned long long* mbox, float* __restrict__ out,
                                             unsigned short* __restrict__ feats,
                                             const float* __restrict__ fcW, unsigned short* __restrict__ fcWb) {
  const int tid = threadIdx.x;
  if (blockIdx.x >= 8) {
    const size_t stride = (size_t)(gridDim.x - 8) * 512 * 8;
    for (size_t i = ((size_t)(blockIdx.x - 8) * 512 + tid) * 8; i < 32768000ull; i += stride) {
      float4 a = *(const float4*)(fcW + i);
      float4 b = *(const float4*)(fcW + i + 4);
      short8 v;
      v[0] = bf16r(a.x); v[1] = bf16r(a.y); v[2] = bf16r(a.z); v[3] = bf16r(a.w);
      v[4] = bf16r(b.x); v[5] = bf16r(b.y); v[6] = bf16r(b.z); v[7] = bf16r(b.w);
      *(short8*)(fcWb + i) = v;
    }
    return;
  }
  const int blk = blockIdx.x;
  const int w = tid >> 6, l = tid & 63;
  const int jt = w & 3, kh = w >> 2;
  const int j16 = blk * 64 + jt * 16;
  const int r = l & 15;   // A row (= batch b), valid r<8
  const int g = l >> 4;   // k-group
  const int n = l & 15;   // B col (= j within tile)

  __shared__ unsigned long long stg[2048];  // 16 KB staged h, granule-swizzled
  __shared__ f32x4 Cbuf[4][64];             // cross-K-half partial sums
  __shared__ float hLf[8][64];              // exact fp32 h slice (for out/feats)
  __shared__ unsigned int hL32[8][64];      // packed {hi,lo} bf16 (for publish)

  // ---- preload W fragments (bf16 hi/lo), 8 chunks per wave (proven layout)
  short8 bhi[8], blo[8];
  {
    const float* wrow = &W_hh[(size_t)(j16 + n) * 512];
#pragma unroll
    for (int c8 = 0; c8 < 8; ++c8) {
      int c = kh * 8 + c8;
      const float* wp = wrow + c * 32 + g * 8;
      float4 wa = *(const float4*)wp;
      float4 wb = *(const float4*)(wp + 4);
      float wv[8] = {wa.x, wa.y, wa.z, wa.w, wb.x, wb.y, wb.z, wb.w};
#pragma unroll
      for (int e = 0; e < 8; ++e) {
        unsigned short h = bfh(wv[e]);
        bhi[c8][e] = (short)h;
        blo[c8][e] = (short)bfh(wv[e] - bf2f(h));
      }
    }
  }

  // ---- per-lane epilogue constants (waves 0..3, lanes 0..31)
  float bj = 0.f, xv[4];
  if (w < 4 && l < 32) {
    bj = b_hh[j16 + n];
#pragma unroll
    for (int i = 0; i < 4; ++i)
      xv[i] = xin[((size_t)(g * 4 + i) * 512 + 0) * 512 + j16 + n];  // t=0
  }
  const int mylen = lengths[(tid >> 6) & 7];  // b = tid>>6 for out-store phase

  __syncthreads();

  // granule swizzle: LDS granule = memGran ^ ((memGran>>6)&3). Preserves 32B
  // granules; read side memGran>>6 == r -> XOR key r&3. (R4-proven)
  const int sgran = tid ^ ((tid >> 6) & 3);

  for (int t = 0; t < 512; ++t) {
    // ======== per-lane sentinel spin on own 32B, stage to LDS, re-sentinel ======
    {
      unsigned long long* src = mbox + ((size_t)blk * 16 + (t & 15)) * 2048 + tid * 4;
      u32x4 A, B2;
      int guard = 0;
      while (true) {
        asm volatile(
            "global_load_dwordx4 %0, %2, off sc0 sc1\n\t"
            "global_load_dwordx4 %1, %2, off offset:16 sc0 sc1\n\t"
            "s_waitcnt vmcnt(0)"
            : "=&v"(A), "=&v"(B2)
            : "v"(src)
            : "memory");
        bool ok = true;
#pragma unroll
        for (int q = 0; q < 4; ++q) ok = ok && (A[q] != 0xFFFFFFFFu) && (B2[q] != 0xFFFFFFFFu);
        if (ok || ++guard == (1 << 20)) break;  // guard -> visible absmax failure
      }
      stg[sgran * 4 + 0] = (unsigned long long)A[0] | ((unsigned long long)A[1] << 32);
      stg[sgran * 4 + 1] = (unsigned long long)A[2] | ((unsigned long long)A[3] << 32);
      stg[sgran * 4 + 2] = (unsigned long long)B2[0] | ((unsigned long long)B2[1] << 32);
      stg[sgran * 4 + 3] = (unsigned long long)B2[2] | ((unsigned long long)B2[3] << 32);
      u32x4 S;
      S[0] = S[1] = S[2] = S[3] = 0xFFFFFFFFu;
      asm volatile(
          "global_store_dwordx4 %0, %1, off sc0 sc1\n\t"
          "global_store_dwordx4 %0, %1, off offset:16 sc0 sc1"
          :: "v"(src), "v"(S)
          : "memory");
      bar_lds();  // B0: staging complete
    }

    // ================ MFMA from LDS-staged fragments ================
    f32x4 acc0 = {}, acc1 = {};
#pragma unroll
    for (int c8 = 0; c8 < 8; ++c8) {
      FragU ah, al;
      if (r < 8) {
        int gran = r * 64 + kh * 32 + c8 * 4 + g;
        int gs = (gran ^ (r & 3)) * 4;
        unsigned long long u0 = stg[gs + 0], u1 = stg[gs + 1];
        unsigned long long u2 = stg[gs + 2], u3 = stg[gs + 3];
        ah.u[0] = (unsigned)u0; al.u[0] = (unsigned)(u0 >> 32);
        ah.u[1] = (unsigned)u1; al.u[1] = (unsigned)(u1 >> 32);
        ah.u[2] = (unsigned)u2; al.u[2] = (unsigned)(u2 >> 32);
        ah.u[3] = (unsigned)u3; al.u[3] = (unsigned)(u3 >> 32);
      } else {
        ah.u[0] = ah.u[1] = ah.u[2] = ah.u[3] = 0u;
        al.u[0] = al.u[1] = al.u[2] = al.u[3] = 0u;
      }
      if (c8 & 1) {
        acc1 = __builtin_amdgcn_mfma_f32_16x16x32_bf16(ah.s, bhi[c8], acc1, 0, 0, 0);
        acc1 = __builtin_amdgcn_mfma_f32_16x16x32_bf16(ah.s, blo[c8], acc1, 0, 0, 0);
        acc1 = __builtin_amdgcn_mfma_f32_16x16x32_bf16(al.s, bhi[c8], acc1, 0, 0, 0);
      } else {
        acc0 = __builtin_amdgcn_mfma_f32_16x16x32_bf16(ah.s, bhi[c8], acc0, 0, 0, 0);
        acc0 = __builtin_amdgcn_mfma_f32_16x16x32_bf16(ah.s, blo[c8], acc0, 0, 0, 0);
        acc0 = __builtin_amdgcn_mfma_f32_16x16x32_bf16(al.s, bhi[c8], acc0, 0, 0, 0);
      }
    }
    f32x4 tot = acc0 + acc1;

    // ================ cross-K-half reduce + tanh ================
    if (w >= 4) Cbuf[w - 4][l] = tot;
    bar_lds();  // B1
    if (w < 4) {
      tot += Cbuf[w][l];
      if (l < 32) {
#pragma unroll
        for (int i = 0; i < 4; ++i) {
          int b = g * 4 + i;
          float hn = fast_tanh(xv[i] + tot[i] + bj);
          hLf[b][jt * 16 + n] = hn;
          unsigned hi = bfh(hn);
          unsigned lo = bfh(hn - bf2f((unsigned short)hi));
          hL32[b][jt * 16 + n] = hi | (lo << 16);
        }
        int tt = (t < 511) ? t + 1 : 511;
#pragma unroll
        for (int i = 0; i < 4; ++i)
          xv[i] = xin[((size_t)(g * 4 + i) * 512 + tt) * 512 + j16 + n];
      }
    }
    bar_lds();  // B2: hLf / hL32 ready

    // ================ out (fp32) + feats (bf16) store, all 512 threads ==========
    {
      int b = tid >> 6, jl = tid & 63;
      float hv = hLf[b][jl];
      hv = (t < mylen) ? hv : 0.f;
      out[((size_t)b * 512 + t) * 512 + blk * 64 + jl] = hv;
      feats[((size_t)b * 512 + t) * 1024 + blk * 64 + jl] = bfh(hv);
    }

    // ================ publish h_{t+1}: wave w -> mailbox w, 2x dwordx4/lane =====
    if (t < 511) {
      unsigned long long* dst = mbox + ((size_t)w * 16 + ((t + 1) & 15)) * 2048 + blk * 32;
      const int e0 = (l & 15) * 4;
#pragma unroll
      for (int k2 = 0; k2 < 2; ++k2) {
        int b = (l >> 4) + k2 * 4;
        unsigned a0 = hL32[b][e0 + 0], a1 = hL32[b][e0 + 1];
        unsigned a2 = hL32[b][e0 + 2], a3 = hL32[b][e0 + 3];
        u32x4 val;
        val[0] = (a0 & 0xffffu) | (a1 << 16);
        val[1] = (a0 >> 16) | (a1 & 0xffff0000u);
        val[2] = (a2 & 0xffffu) | (a3 << 16);
        val[3] = (a2 >> 16) | (a3 & 0xffff0000u);
        unsigned long long* p = dst + (size_t)b * 256 + (l & 15) * 2;
        asm volatile("global_store_dwordx4 %0, %1, off sc0 sc1" :: "v"(p), "v"(val) : "memory");
      }
    }
    // no trailing barrier: next step's B0 paces LDS reuse (reads@t < B1 < writes@t+1).
  }
}

// ---------------------------------------------------------------- K3: q = out@W1^T ; kT = out@W2^T + b  (merged: MODE = blockIdx.z)
__global__ __launch_bounds__(256) void k_qk(const float* __restrict__ out, const float* __restrict__ attn_W,
                                            const float* __restrict__ attn_b, float* __restrict__ qdst,
                                            float* __restrict__ kdst) {
  __shared__ float At[64][128];
  __shared__ float Bt[128][64];
  const int tid = threadIdx.x;
  const int MODE = blockIdx.z;
  const int bt0 = blockIdx.x * 64, j0 = blockIdx.y * 64;
  const int ty = tid >> 4, tx = tid & 15;
  const int lane = tid & 63, cgrp = tid >> 6;
  float acc[4][4] = {};
  for (int kc = 0; kc < 512; kc += 128) {
#pragma unroll
    for (int rr = 0; rr < 8; ++rr) {
      int row = rr * 8 + (tid >> 5);
      int col = (tid & 31) * 4;
      *(float4*)&At[row][col] = *(const float4*)&out[((size_t)bt0 + row) * 512 + kc + col];
    }
#pragma unroll
    for (int cc = 0; cc < 8; ++cc) {
      int col = cgrp * 32 + cc * 4;
      float4 v = *(const float4*)&attn_W[(size_t)(j0 + lane) * 1024 + (MODE ? 512 : 0) + kc + col];
      Bt[col + 0][lane] = v.x; Bt[col + 1][lane] = v.y;
      Bt[col + 2][lane] = v.z; Bt[col + 3][lane] = v.w;
    }
    __syncthreads();
    for (int kk = 0; kk < 128; ++kk) {
      float bv[4];
#pragma unroll
      for (int c = 0; c < 4; ++c) bv[c] = Bt[kk][tx * 4 + c];
#pragma unroll
      for (int a = 0; a < 4; ++a) {
        float av = At[ty * 4 + a][kk];
#pragma unroll
        for (int c = 0; c < 4; ++c) acc[a][c] = fmaf(av, bv[c], acc[a][c]);
      }
    }
    __syncthreads();
  }
#pragma unroll
  for (int a = 0; a < 4; ++a) {
    int bt = bt0 + ty * 4 + a;
#pragma unroll
    for (int c = 0; c < 4; ++c) {
      int j = j0 + tx * 4 + c;
      if (MODE == 0) {
        qdst[(size_t)bt * 512 + j] = acc[a][c];
      } else {
        int bb = bt >> 9, tt = bt & 511;
        kdst[((size_t)bb * 512 + j) * 512 + tt] = acc[a][c] + attn_b[j];
      }
    }
  }
}

// ---------------------------------------------------------------- K4: p[b][t][s] = exp(score-20) masked  (+ fused rowsum -> invl)
__global__ __launch_bounds__(256) void k_scores(const float* __restrict__ q, const float* __restrict__ kT,
                                                const float* __restrict__ attn_v, const float* __restrict__ attn_v_b,
                                                const int* __restrict__ lengths, float* __restrict__ pbuf,
                                                float* __restrict__ invl) {
  const int b = blockIdx.x, t0 = blockIdx.y * 4;
  const int tid = threadIdx.x;
  __shared__ float qL[4][512];
  __shared__ float vL[512];
  __shared__ float red[4][4];
  for (int i = tid; i < 4 * 512; i += 256) {
    int rr = i >> 9, h = i & 511;
    qL[rr][h] = q[((size_t)b * 512 + t0 + rr) * 512 + h];
  }
  for (int i = tid; i < 512; i += 256) vL[i] = attn_v[i];
  const float vb = attn_v_b[0];
  const int len = lengths[b];
  __syncthreads();
  const int s_hi = min(t0 + 3, len - 1);
  const float* kTb = kT + (size_t)b * 512 * 512;
  float psum[4] = {0.f, 0.f, 0.f, 0.f};
#pragma unroll
  for (int si = 0; si < 2; ++si) {
    int s = tid + si * 256;
    float acc[4] = {0.f, 0.f, 0.f, 0.f};
    if (s <= s_hi) {
      for (int h = 0; h < 512; ++h) {
        float kv = kTb[(size_t)h * 512 + s];
        float vh = vL[h];
#pragma unroll
        for (int rr = 0; rr < 4; ++rr) acc[rr] = fmaf(vh, fast_tanh(qL[rr][h] + kv), acc[rr]);
      }
    }
#pragma unroll
    for (int rr = 0; rr < 4; ++rr) {
      int t = t0 + rr;
      bool valid = (s <= t) && (s < len);
      float p = valid ? __expf(acc[rr] + vb - 20.f) : 0.f;
      pbuf[((size_t)b * 512 + t) * 512 + s] = p;
      psum[rr] += p;
    }
  }
  const int wv = tid >> 6, ln = tid & 63;
#pragma unroll
  for (int rr = 0; rr < 4; ++rr) {
    float v = psum[rr];
#pragma unroll
    for (int m = 1; m < 64; m <<= 1) v += __shfl_xor(v, m);
    if (ln == 0) red[wv][rr] = v;
  }
  __syncthreads();
  if (tid < 4) {
    float s = red[0][tid] + red[1][tid] + red[2][tid] + red[3][tid];
    invl[(size_t)b * 512 + t0 + tid] = 1.0f / s;
  }
}

// ---------------------------------------------------------------- K6: feats[:, 512:1024] = bf16((p @ out) * invl)
__global__ __launch_bounds__(256) void k_context(const float* __restrict__ pbuf, const float* __restrict__ out,
                                                 const float* __restrict__ invl, unsigned short* __restrict__ feats) {
  __shared__ float Pt[64][128];
  __shared__ float Ot[128][64];
  const int b = blockIdx.z, t0 = blockIdx.y * 64, h0 = blockIdx.x * 64;
  const int tid = threadIdx.x, ty = tid >> 4, tx = tid & 15;
  float acc[4][4] = {};
  for (int sc = 0; sc < 512; sc += 128) {
#pragma unroll
    for (int rr = 0; rr < 8; ++rr) {
      int row = rr * 8 + (tid >> 5);
      int col = (tid & 31) * 4;
      *(float4*)&Pt[row][col] = *(const float4*)&pbuf[((size_t)b * 512 + t0 + row) * 512 + sc + col];
    }
#pragma unroll
    for (int rr = 0; rr < 8; ++rr) {
      int srow = rr * 16 + (tid >> 4);
      int col = (tid & 15) * 4;
      *(float4*)&Ot[srow][col] = *(const float4*)&out[((size_t)b * 512 + sc + srow) * 512 + h0 + col];
    }
    __syncthreads();
    for (int kk = 0; kk < 128; ++kk) {
      float ov[4];
#pragma unroll
      for (int c = 0; c < 4; ++c) ov[c] = Ot[kk][tx * 4 + c];
#pragma unroll
      for (int a = 0; a < 4; ++a) {
        float pv = Pt[ty * 4 + a][kk];
#pragma unroll
        for (int c = 0; c < 4; ++c) acc[a][c] = fmaf(pv, ov[c], acc[a][c]);
      }
    }
    __syncthreads();
  }
#pragma unroll
  for (int a = 0; a < 4; ++a) {
    int t = t0 + ty * 4 + a;
    float il = invl[b * 512 + t];
#pragma unroll
    for (int c = 0; c < 4; ++c) {
      int h = h0 + tx * 4 + c;
      feats[((size_t)b * 512 + t) * 1024 + 512 + h] = (unsigned short)bf16r(acc[a][c] * il);
    }
  }
}

// ---------------------------------------------------------------- K7: logits = feats @ fc_W^T + fc_b (bf16 MFMA, XCD-swizzled)
__global__ __launch_bounds__(256) void k_logits(const unsigned short* __restrict__ A,
                                                const unsigned short* __restrict__ Bw,
                                                const float* __restrict__ bias, float* __restrict__ C) {
  const int linb = blockIdx.x;
  const int xcd = linb & 7, pos = linb >> 3;
  const int m0 = (xcd * 4 + (pos & 3)) * 128;
  const int n0 = (pos >> 2) * 128;
  __shared__ unsigned short As[128 * 64];
  __shared__ unsigned short Bs[128 * 64];
  const int tid = threadIdx.x;
  const int wave = tid >> 6, lane = tid & 63;
  const int wm = (wave >> 1) * 64, wn = (wave & 1) * 64;
  const int lo16 = lane & 15, oct = lane >> 4;
  f32x4 acc[4][4] = {};
  for (int kt = 0; kt < 1024; kt += 64) {
#pragma unroll
    for (int i = 0; i < 4; ++i) {
      int ci = wave * 4 + i;
      int mrow = ci * 8 + (lane >> 3);
      int k8 = (lane & 7) * 8;
      glds16(&A[(size_t)(m0 + mrow) * 1024 + kt + k8], &As[ci * 512]);
      glds16(&Bw[(size_t)(n0 + mrow) * 1024 + kt + k8], &Bs[ci * 512]);
    }
    __syncthreads();
#pragma unroll
    for (int kk = 0; kk < 2; ++kk) {
      short8 af[4], bf[4];
#pragma unroll
      for (int i = 0; i < 4; ++i)
        af[i] = *(const short8*)&As[(wm + i * 16 + lo16) * 64 + kk * 32 + oct * 8];
#pragma unroll
      for (int jn = 0; jn < 4; ++jn)
        bf[jn] = *(const short8*)&Bs[(wn + jn * 16 + lo16) * 64 + kk * 32 + oct * 8];
#pragma unroll
      for (int i = 0; i < 4; ++i)
#pragma unroll
        for (int jn = 0; jn < 4; ++jn)
          acc[i][jn] = __builtin_amdgcn_mfma_f32_16x16x32_bf16(af[i], bf[jn], acc[i][jn], 0, 0, 0);
    }
    __syncthreads();
  }
#pragma unroll
  for (int jn = 0; jn < 4; ++jn) {
    int nn = n0 + wn + jn * 16 + lo16;
    float bv = bias[nn];
#pragma unroll
    for (int i = 0; i < 4; ++i) {
      int mbase = m0 + wm + i * 16 + oct * 4;
#pragma unroll
      for (int rr = 0; rr < 4; ++rr)
        C[(size_t)(mbase + rr) * 32000 + nn] = acc[i][jn][rr] + bv;
    }
  }
}

// ---------------------------------------------------------------- launch
extern "C" void kernel_launch(void* const* d_in, const int* in_sizes, int n_in,
                              void* d_out, int out_size, void* d_ws, size_t ws_size,
                              hipStream_t stream) {
  const int* x = (const int*)d_in[0];
  const int* lengths = (const int*)d_in[1];
  const float* embed = (const float*)d_in[2];
  const float* W_ih = (const float*)d_in[3];
  const float* W_hh = (const float*)d_in[4];
  const float* b_ih = (const float*)d_in[5];
  const float* b_hh = (const float*)d_in[6];
  const float* attn_W = (const float*)d_in[7];
  const float* attn_b = (const float*)d_in[8];
  const float* attn_v = (const float*)d_in[9];
  const float* attn_v_b = (const float*)d_in[10];
  const float* fc_W = (const float*)d_in[11];
  const float* fc_b = (const float*)d_in[12];
  float* logits = (float*)d_out;

  char* ws = (char*)d_ws;
  const size_t MB8 = 8388608;
  float* xin  = (float*)(ws);
  float* outp = (float*)(ws + 1 * MB8);
  float* q    = (float*)(ws + 2 * MB8);
  float* kT   = (float*)(ws + 3 * MB8);
  float* pbuf = (float*)(ws + 4 * MB8);
  float* invl = (float*)(ws + 5 * MB8);
  unsigned short* feats = (unsigned short*)(ws + 5 * MB8 + 16384);
  unsigned short* fcWb  = (unsigned short*)(ws + 6 * MB8 + 16384);
  // mbox aliases pbuf: [8 dst][16 slots][16 KB] = 2 MB. Dead once k_rnn
  // completes; k_scores then fully overwrites pbuf.
  unsigned long long* mbox = (unsigned long long*)pbuf;

  hipMemsetAsync(mbox, 0xFF, 8 * 16 * 16384, stream);  // sentinel all ring slots
  for (int d = 0; d < 8; ++d)                          // slot 0 of each mailbox = h_0 = 0
    hipMemsetAsync((char*)mbox + (size_t)d * 16 * 16384, 0x00, 16384, stream);
  k_xin<<<dim3(64, 8), 256, 0, stream>>>(x, embed, W_ih, b_ih, xin);
  k_rnn<<<136, 512, 0, stream>>>(xin, W_hh, b_hh, lengths, mbox, outp, feats, fc_W, fcWb);
  k_qk<<<dim3(64, 8, 2), 256, 0, stream>>>(outp, attn_W, attn_b, q, kT);
  k_scores<<<dim3(8, 128), 256, 0, stream>>>(q, kT, attn_v, attn_v_b, lengths, pbuf, invl);
  k_context<<<dim3(8, 8, 8), 256, 0, stream>>>(pbuf, outp, invl, feats);
  k_logits<<<8000, 256, 0, stream>>>(feats, fcWb, fc_b, logits);
}